// Round 1
// baseline (24900.206 us; speedup 1.0000x reference)
//
#include <hip/hip_runtime.h>

typedef unsigned short u16;
typedef short bf16x8 __attribute__((ext_vector_type(8)));
typedef float f32x4 __attribute__((ext_vector_type(4)));

// B=32, S=T=100, E=512, H=512, VT=32000. fp32 in global; bf16 as MFMA operands.
// gate order (PyTorch): i,f,g,o rows of [4H, *] weights.

__device__ __forceinline__ u16 f2bf(float f) {
    unsigned u = __builtin_bit_cast(unsigned, f);
    return (u16)((u + 0x7FFFu + ((u >> 16) & 1u)) >> 16);
}
__device__ __forceinline__ float sigm(float x) { return 1.0f / (1.0f + __expf(-x)); }
__device__ __forceinline__ float tanh_(float x) { return 2.0f / (1.0f + __expf(-2.0f * x)) - 1.0f; }
__device__ __forceinline__ f32x4 mfma16(bf16x8 a, bf16x8 b, f32x4 c) {
    return __builtin_amdgcn_mfma_f32_16x16x32_bf16(a, b, c, 0, 0, 0);
}
__device__ __forceinline__ uint4 pack8(float4 a, float4 b) {
    union { u16 h[8]; uint4 v; } u;
    u.h[0] = f2bf(a.x); u.h[1] = f2bf(a.y); u.h[2] = f2bf(a.z); u.h[3] = f2bf(a.w);
    u.h[4] = f2bf(b.x); u.h[5] = f2bf(b.y); u.h[6] = f2bf(b.z); u.h[7] = f2bf(b.w);
    return u.v;
}

// ---- device-scope grid barrier (sense = monotone generation counter) ----
// Safe for non-cooperative launch iff all blocks are co-resident (grid<=256,
// LDS/block <= 80KB => every block gets a CU). atomics are agent(device) scope.
__device__ __forceinline__ void gbar(unsigned* cnt, unsigned* flg, unsigned gen, unsigned nb) {
    __syncthreads();                       // drains vmcnt -> this block's stores visible
    if (threadIdx.x == 0) {
        __threadfence();                   // release: writeback L2 (cross-XCD)
        unsigned a = __hip_atomic_fetch_add(cnt, 1u, __ATOMIC_ACQ_REL, __HIP_MEMORY_SCOPE_AGENT);
        if (a == nb - 1u) {
            __hip_atomic_store(cnt, 0u, __ATOMIC_RELAXED, __HIP_MEMORY_SCOPE_AGENT);
            __hip_atomic_store(flg, gen, __ATOMIC_RELEASE, __HIP_MEMORY_SCOPE_AGENT);
        } else {
            int guard = 0;
            while (__hip_atomic_load(flg, __ATOMIC_ACQUIRE, __HIP_MEMORY_SCOPE_AGENT) < gen) {
                __builtin_amdgcn_s_sleep(1);
                if (++guard > (1 << 20)) break;   // escape hatch: fail loud, never hang
            }
        }
        __threadfence();                   // acquire: invalidate L1/L2 for plain loads
    }
    __syncthreads();
}

// ---------------- weight conversion ----------------
__global__ __launch_bounds__(256) void convert_f2b(const float* __restrict__ src,
                                                   u16* __restrict__ dst, int n) {
    int i = (blockIdx.x * 256 + threadIdx.x) * 4;
    if (i < n) {
        float4 v = *(const float4*)(src + i);
        dst[i] = f2bf(v.x); dst[i + 1] = f2bf(v.y);
        dst[i + 2] = f2bf(v.z); dst[i + 3] = f2bf(v.w);
    }
}
// W2[n][k] = k<1024 ? dec_Wih[n][512+k] : dec_Whh[n][k-1024]   (n in [0,2048))
__global__ __launch_bounds__(256) void build_w2(const float* __restrict__ Wih,
                                                const float* __restrict__ Whh,
                                                u16* __restrict__ W2) {
    int n = blockIdx.x;
    for (int i = 0; i < 6; i++) {
        int k = i * 256 + threadIdx.x;
        float v = (k < 1024) ? Wih[(size_t)n * 1536 + 512 + k]
                             : Whh[(size_t)n * 512 + (k - 1024)];
        W2[(size_t)n * 1536 + k] = f2bf(v);
    }
}
// a1Wh[n][k] = att1_W[n][1024+k], bf16, n<1536, k<512
__global__ __launch_bounds__(256) void build_a1wh(const float* __restrict__ a1W,
                                                  u16* __restrict__ dst) {
    int n = blockIdx.x;
    for (int i = 0; i < 2; i++) {
        int k = i * 256 + threadIdx.x;
        dst[(size_t)n * 512 + k] = f2bf(a1W[(size_t)n * 1536 + 1024 + k]);
    }
}

// ---------------- embedding gathers (fp32) ----------------
__global__ __launch_bounds__(256) void embed_src(const int* __restrict__ tok,
                                                 const float* __restrict__ emb,
                                                 float* __restrict__ xs) {
    int g = blockIdx.x * 256 + threadIdx.x;      // 3200*64
    int row = g >> 6, c = (g & 63) * 8;
    int s = row >> 5, b = row & 31;
    int id = tok[b * 100 + s];
    *(float4*)(xs + (size_t)row * 512 + c) = *(const float4*)(emb + (size_t)id * 512 + c);
    *(float4*)(xs + (size_t)row * 512 + c + 4) = *(const float4*)(emb + (size_t)id * 512 + c + 4);
}
__global__ __launch_bounds__(256) void embed_tgt(const int* __restrict__ tok,
                                                 const float* __restrict__ emb,
                                                 float* __restrict__ cls_in) {
    int g = blockIdx.x * 256 + threadIdx.x;
    int row = g >> 6, c = (g & 63) * 8;
    int t = row >> 5, b = row & 31;
    int id = tok[b * 100 + t];
    size_t dst = ((size_t)b * 100 + t) * 2048 + c;
    *(float4*)(cls_in + dst) = *(const float4*)(emb + (size_t)id * 512 + c);
    *(float4*)(cls_in + dst + 4) = *(const float4*)(emb + (size_t)id * 512 + c + 4);
}

// ---------------- MFMA GEMM: C[M,N] = A[M,K]@W[N,K]^T (+bias)(+relu) ----------------
__global__ __launch_bounds__(256) void gemm_bt(const float* __restrict__ A, int lda,
                                               const float* __restrict__ W, int ldw,
                                               float* __restrict__ C,
                                               const float* __restrict__ bias0,
                                               const float* __restrict__ bias1,
                                               int N, int K, int relu) {
    __shared__ __align__(16) u16 As[128][40];
    __shared__ __align__(16) u16 Bs[128][40];
    int tid = threadIdx.x;
    int lane = tid & 63, w = tid >> 6;
    int wm = w & 1, wn = w >> 1;
    int l15 = lane & 15, q = lane >> 4;
    f32x4 acc[4][4] = {};
    int sr = tid >> 2, sc = (tid & 3) * 8;
    const float* Ar0 = A + (size_t)(blockIdx.x * 128 + sr) * lda;
    const float* Ar1 = Ar0 + (size_t)64 * lda;
    const float* Wr0 = W + (size_t)(blockIdx.y * 128 + sr) * ldw;
    const float* Wr1 = Wr0 + (size_t)64 * ldw;
    for (int kb = 0; kb < K; kb += 32) {
        *(uint4*)&As[sr][sc] = pack8(*(const float4*)(Ar0 + kb + sc), *(const float4*)(Ar0 + kb + sc + 4));
        *(uint4*)&As[sr + 64][sc] = pack8(*(const float4*)(Ar1 + kb + sc), *(const float4*)(Ar1 + kb + sc + 4));
        *(uint4*)&Bs[sr][sc] = pack8(*(const float4*)(Wr0 + kb + sc), *(const float4*)(Wr0 + kb + sc + 4));
        *(uint4*)&Bs[sr + 64][sc] = pack8(*(const float4*)(Wr1 + kb + sc), *(const float4*)(Wr1 + kb + sc + 4));
        __syncthreads();
        bf16x8 af[4], bfr[4];
        for (int i = 0; i < 4; i++) af[i] = *(const bf16x8*)&As[wm * 64 + i * 16 + l15][q * 8];
        for (int j = 0; j < 4; j++) bfr[j] = *(const bf16x8*)&Bs[wn * 64 + j * 16 + l15][q * 8];
        for (int i = 0; i < 4; i++)
            for (int j = 0; j < 4; j++) acc[i][j] = mfma16(af[i], bfr[j], acc[i][j]);
        __syncthreads();
    }
    for (int j = 0; j < 4; j++) {
        int n = blockIdx.y * 128 + wn * 64 + j * 16 + l15;
        float bv = 0.f;
        if (bias0) bv += bias0[n];
        if (bias1) bv += bias1[n];
        for (int i = 0; i < 4; i++) {
            int mb = blockIdx.x * 128 + wm * 64 + i * 16 + q * 4;
            for (int r = 0; r < 4; r++) {
                float v = acc[i][j][r] + bv;
                if (relu) v = v > 0.f ? v : 0.f;
                C[(size_t)(mb + r) * N + n] = v;
            }
        }
    }
}

// ---------------- persistent encoder: all 100 steps, Whh pinned in LDS ----------------
// grid = 128 blocks x 64 thr. block = (dir, mt, jt) as before. per-dir grid barrier.
__global__ __launch_bounds__(64) void enc_persist(const u16* __restrict__ whhf,
                                                  const u16* __restrict__ whhb,
                                                  const float* __restrict__ Pf,
                                                  const float* __restrict__ Pb,
                                                  u16* __restrict__ hb,       // [parity][dir][32][512] bf16
                                                  float* __restrict__ cenc,   // [dir][32][512] fp32
                                                  float* __restrict__ ef32,   // [b][s][1024] fp32
                                                  unsigned* __restrict__ bar) {
    __shared__ __align__(16) u16 ws[64 * 512];   // 64KB: rows (g*16+r15) of this block's Whh slice
    int blk = blockIdx.x;
    int dir = blk >> 6, mt = (blk >> 5) & 1, jt = blk & 31;
    int lane = threadIdx.x, l15 = lane & 15, q = lane >> 4;
    const u16* whh = dir ? whhb : whhf;
    const float* P = dir ? Pb : Pf;
    unsigned* cnt = bar + dir * 32;      // 128B apart per dir
    unsigned* flg = cnt + 16;
    // one-time: stage weights into LDS, XOR-swizzled (row stride 1KB == 0 mod 128B)
    {
        int R = lane, g = R >> 4, r15 = R & 15;
        const u16* src = whh + (size_t)(g * 512 + jt * 16 + r15) * 512;
        int swz = (R & 7) * 8;
        for (int c = 0; c < 64; c++)
            *(uint4*)&ws[R * 512 + ((c * 8) ^ swz)] = *(const uint4*)(src + c * 8);
    }
    __syncthreads();
    int swzr = (l15 & 7) * 8;
    unsigned gen = 0;
    for (int t = 0; t < 100; t++) {
        const u16* hin = hb + ((t & 1) ? 2 * 32 * 512 : 0) + dir * 32 * 512;
        u16* hout = hb + ((t & 1) ? 0 : 2 * 32 * 512);
        int s = dir ? (99 - t) : t;
        f32x4 acc[4] = {};
        const u16* arow = hin + (mt * 16 + l15) * 512 + q * 8;
        for (int kb = 0; kb < 512; kb += 32) {
            bf16x8 a = *(const bf16x8*)(arow + kb);
            for (int g = 0; g < 4; g++) {
                bf16x8 b = *(const bf16x8*)&ws[(g * 16 + l15) * 512 + ((kb + q * 8) ^ swzr)];
                acc[g] = mfma16(a, b, acc[g]);
            }
        }
        int j = jt * 16 + l15;
        for (int r = 0; r < 4; r++) {
            int b_ = mt * 16 + q * 4 + r;
            const float* Pr = P + ((size_t)s * 32 + b_) * 2048;
            float gi = acc[0][r] + Pr[j];
            float gf = acc[1][r] + Pr[512 + j];
            float gg = acc[2][r] + Pr[1024 + j];
            float go = acc[3][r] + Pr[1536 + j];
            float* cp = cenc + (dir * 32 + b_) * 512 + j;
            float cn = sigm(gf) * (*cp) + sigm(gi) * tanh_(gg);
            float hn = sigm(go) * tanh_(cn);
            *cp = cn;
            hout[(dir * 32 + b_) * 512 + j] = f2bf(hn);
            ef32[((size_t)b_ * 100 + s) * 1024 + dir * 512 + j] = hn;
        }
        if (t < 99) { gen++; gbar(cnt, flg, gen, 64); }
    }
}

// decoder init: h/c from final forward-direction encoder state
__global__ __launch_bounds__(256) void init_dec(const u16* __restrict__ h_enc,
                                                const float* __restrict__ c_enc,
                                                u16* __restrict__ xcat0,
                                                float* __restrict__ c_dec) {
    int idx = blockIdx.x * 256 + threadIdx.x;    // 16384 = 32*512
    int b = idx >> 9, j = idx & 511;
    xcat0[b * 1536 + 1024 + j] = h_enc[b * 512 + j];
    c_dec[idx] = c_enc[idx];
}

// ---------------- persistent decoder: all 100 steps, W2 + a1Wh pinned in LDS ----------
// grid = 256 blocks x 256 thr.
// phase A (blocks<96, waves 0-1): pp = h @ a1Wh^T      -> grid bar
// phase B (all, 1024 waves): scores                    -> grid bar
// phase C (all): softmax + ctx (b=B>>3, 128-col chunk) -> grid bar
// phase D (blocks<128, waves 0-1): gates + LSTM update -> grid bar
__global__ __launch_bounds__(256) void dec_persist(const u16* __restrict__ W2g,
                                                   const u16* __restrict__ a1whg,
                                                   const float* __restrict__ encpre,
                                                   const float* __restrict__ ef32,
                                                   const float* __restrict__ Dpre,
                                                   const float* __restrict__ a2W,
                                                   const float* __restrict__ a2b,
                                                   float* __restrict__ pp,
                                                   float* __restrict__ sc,
                                                   u16* __restrict__ xcat,
                                                   float* __restrict__ cdec,
                                                   float* __restrict__ clsin,
                                                   unsigned* __restrict__ bar) {
    __shared__ __align__(16) u16 w2s[16 * 1536];   // 48KB: W2 rows (g*4+jo) for j = B0*4+jo
    __shared__ __align__(16) u16 a1s[16 * 512];    // 16KB: a1Wh rows n0..n0+15
    __shared__ float a2s[1536];
    __shared__ float gbuf[32 * 16];
    __shared__ float sm[100];
    __shared__ float rmax_s, rsum_s;
    int B0 = blockIdx.x, tid = threadIdx.x;
    int w = tid >> 6, lane = tid & 63, l15 = lane & 15, q = lane >> 4;
    unsigned* cnt = bar;
    unsigned* flg = bar + 16;
    int swzr = (l15 & 7) * 8;

    for (int k = tid; k < 1536; k += 256) a2s[k] = a2W[k];
    float a2bv = a2b[0];
    if (B0 < 128) {      // W2 slice (row n <-> global row (n>>2)*512 + B0*4 + (n&3))
        int j0 = B0 * 4;
        for (int r = 0; r < 16; r++) {
            if (tid < 192) {
                int grow = (r >> 2) * 512 + j0 + (r & 3);
                *(uint4*)&w2s[r * 1536 + ((tid * 8) ^ ((r & 7) * 8))] =
                    *(const uint4*)(W2g + (size_t)grow * 1536 + tid * 8);
            }
        }
    }
    if (B0 < 96) {       // a1Wh slice rows n0..n0+15
        int n0 = B0 * 16;
        for (int r = 0; r < 16; r++) {
            if (tid < 64) {
                *(uint4*)&a1s[r * 512 + ((tid * 8) ^ ((r & 7) * 8))] =
                    *(const uint4*)(a1whg + (size_t)(n0 + r) * 512 + tid * 8);
            }
        }
    }
    __syncthreads();

    unsigned gen = 0;
    for (int t = 0; t < 100; t++) {
        u16* xin = xcat + (size_t)(t & 1) * 32 * 1536;
        u16* xnext = xcat + (size_t)((t + 1) & 1) * 32 * 1536;

        // ---- phase A: pp[32][1536] = h @ a1Wh^T (same accumulation order as dpp_step)
        if (B0 < 96 && w < 2) {
            int m = w;
            f32x4 acc = {};
            const u16* arow = xin + (m * 16 + l15) * 1536 + 1024 + q * 8;
            for (int kb = 0; kb < 512; kb += 32) {
                bf16x8 a = *(const bf16x8*)(arow + kb);
                bf16x8 b = *(const bf16x8*)&a1s[l15 * 512 + ((kb + q * 8) ^ swzr)];
                acc = mfma16(a, b, acc);
            }
            int n = B0 * 16 + l15;
            for (int r = 0; r < 4; r++) pp[(m * 16 + q * 4 + r) * 1536 + n] = acc[r];
        }
        gen++; gbar(cnt, flg, gen, 256);

        // ---- phase B: scores[b*100+s] = a2b + sum_k a2[k]*relu(encpre + pp)
        {
            int gw = B0 * 4 + w;     // 0..1023
            for (int i = 0; i < 4; i++) {
                int row = gw + i * 1024;
                if (row < 3200) {
                    int b = row / 100;
                    const float* ep = encpre + (size_t)row * 1536;
                    const float* pb = pp + b * 1536;
                    float acc = 0.f;
                    for (int ii = 0; ii < 24; ii++) {
                        int k = ii * 64 + lane;
                        float v = ep[k] + pb[k];
                        v = fmaxf(v, 0.f);
                        acc += v * a2s[k];
                    }
                    for (int off = 32; off; off >>= 1) acc += __shfl_xor(acc, off);
                    if (lane == 0) sc[row] = acc + a2bv;
                }
            }
        }
        gen++; gbar(cnt, flg, gen, 256);

        // ---- phase C: softmax over s + ctx; b = B0>>3, 128-col chunk
        {
            int b = B0 >> 3, kc = (B0 & 7) * 128;
            if (tid < 100) sm[tid] = sc[b * 100 + tid];
            __syncthreads();
            if (tid < 64) {
                float mx = -1e30f;
                for (int s2 = tid; s2 < 100; s2 += 64) mx = fmaxf(mx, sm[s2]);
                for (int o = 32; o; o >>= 1) mx = fmaxf(mx, __shfl_xor(mx, o));
                if (tid == 0) rmax_s = mx;
            }
            __syncthreads();
            if (tid < 100) sm[tid] = __expf(sm[tid] - rmax_s);
            __syncthreads();
            if (tid < 64) {
                float s3 = 0.f;
                for (int s2 = tid; s2 < 100; s2 += 64) s3 += sm[s2];
                for (int o = 32; o; o >>= 1) s3 += __shfl_xor(s3, o);
                if (tid == 0) rsum_s = s3;
            }
            __syncthreads();
            if (tid < 128) {
                float inv = 1.0f / rsum_s;
                int k = kc + tid;
                const float* eb = ef32 + (size_t)b * 100 * 1024 + k;
                float acc = 0.f;
                for (int s2 = 0; s2 < 100; s2++) acc += sm[s2] * eb[s2 * 1024];
                acc *= inv;
                xin[b * 1536 + k] = f2bf(acc);
                clsin[((size_t)b * 100 + t) * 2048 + 512 + k] = acc;
            }
        }
        gen++; gbar(cnt, flg, gen, 256);

        // ---- phase D: gates = xcat @ W2^T + Dpre, LSTM update (order == dec_step)
        if (B0 < 128) {
            int j0 = B0 * 4;
            if (w < 2) {
                int m = w;
                f32x4 acc = {};
                const u16* arow = xin + (m * 16 + l15) * 1536 + q * 8;
                for (int kb = 0; kb < 1536; kb += 32) {
                    bf16x8 a = *(const bf16x8*)(arow + kb);
                    bf16x8 b = *(const bf16x8*)&w2s[l15 * 1536 + ((kb + q * 8) ^ swzr)];
                    acc = mfma16(a, b, acc);
                }
                for (int r = 0; r < 4; r++) gbuf[(m * 16 + q * 4 + r) * 16 + l15] = acc[r];
            }
            __syncthreads();
            if (tid < 128) {
                int b = tid >> 2, jo = tid & 3, j = j0 + jo;
                const float* Pr = Dpre + ((size_t)b * 100 + t) * 2048;
                float gi = gbuf[b * 16 + jo] + Pr[j];
                float gf = gbuf[b * 16 + 4 + jo] + Pr[512 + j];
                float gg = gbuf[b * 16 + 8 + jo] + Pr[1024 + j];
                float go = gbuf[b * 16 + 12 + jo] + Pr[1536 + j];
                float cv = cdec[b * 512 + j];
                float cn = sigm(gf) * cv + sigm(gi) * tanh_(gg);
                float hn = sigm(go) * tanh_(cn);
                cdec[b * 512 + j] = cn;
                xnext[b * 1536 + 1024 + j] = f2bf(hn);
                clsin[((size_t)b * 100 + t) * 2048 + 1536 + j] = hn;
            }
        }
        if (t < 99) { gen++; gbar(cnt, flg, gen, 256); }
    }
}

extern "C" void kernel_launch(void* const* d_in, const int* in_sizes, int n_in,
                              void* d_out, int out_size, void* d_ws, size_t ws_size,
                              hipStream_t stream) {
    const int* src_tok = (const int*)d_in[0];
    const int* tgt_tok = (const int*)d_in[1];
    const float* src_emb = (const float*)d_in[2];
    const float* tgt_emb = (const float*)d_in[3];
    const float* eWih_f = (const float*)d_in[4];
    const float* eWhh_f = (const float*)d_in[5];
    const float* ebih_f = (const float*)d_in[6];
    const float* ebhh_f = (const float*)d_in[7];
    const float* eWih_b = (const float*)d_in[8];
    const float* eWhh_b = (const float*)d_in[9];
    const float* ebih_b = (const float*)d_in[10];
    const float* ebhh_b = (const float*)d_in[11];
    const float* dWih = (const float*)d_in[12];
    const float* dWhh = (const float*)d_in[13];
    const float* dbih = (const float*)d_in[14];
    const float* dbhh = (const float*)d_in[15];
    const float* a1W = (const float*)d_in[16];
    const float* a1b = (const float*)d_in[17];
    const float* a2W = (const float*)d_in[18];
    const float* a2b = (const float*)d_in[19];
    const float* c1W = (const float*)d_in[20];
    const float* c1b = (const float*)d_in[21];
    const float* c2W = (const float*)d_in[22];
    const float* c2b = (const float*)d_in[23];
    float* out = (float*)d_out;

    char* W = (char*)d_ws;
    size_t off = 0;
    auto alloc = [&](size_t bytes) { size_t o = off; off = (off + bytes + 255) & ~(size_t)255; return o; };
    size_t o_xs     = alloc((size_t)3200 * 512 * 4);
    size_t o_Pf     = alloc((size_t)3200 * 2048 * 4);
    size_t o_Pb     = alloc((size_t)3200 * 2048 * 4);
    size_t o_Dpre   = alloc((size_t)3200 * 2048 * 4);
    size_t o_ef32   = alloc((size_t)3200 * 1024 * 4);
    size_t o_encpre = alloc((size_t)3200 * 1536 * 4);
    size_t o_clsin  = alloc((size_t)3200 * 2048 * 4);
    size_t o_h1     = alloc((size_t)3200 * 1024 * 4);
    size_t o_W2     = alloc((size_t)2048 * 1536 * 2);
    size_t o_whhf   = alloc((size_t)2048 * 512 * 2);
    size_t o_whhb   = alloc((size_t)2048 * 512 * 2);
    size_t o_a1wh   = alloc((size_t)1536 * 512 * 2);
    size_t o_hb     = alloc((size_t)2 * 2 * 32 * 512 * 2);   // [parity][dir][b][k] bf16
    size_t o_cenc   = alloc((size_t)2 * 32 * 512 * 4);
    size_t o_xcat   = alloc((size_t)2 * 32 * 1536 * 2);      // [parity][b][ctx(1024)|h(512)] bf16
    size_t o_cdec   = alloc((size_t)32 * 512 * 4);
    size_t o_pp     = alloc((size_t)32 * 1536 * 4);
    size_t o_sc     = alloc((size_t)3200 * 4);
    size_t o_bar    = alloc(512);                            // grid-barrier counters/flags

    float* xs = (float*)(W + o_xs);
    float* Pf = (float*)(W + o_Pf);
    float* Pb = (float*)(W + o_Pb);
    float* Dpre = (float*)(W + o_Dpre);
    float* ef32 = (float*)(W + o_ef32);
    float* encpre = (float*)(W + o_encpre);
    float* clsin = (float*)(W + o_clsin);
    float* h1 = (float*)(W + o_h1);
    u16* W2 = (u16*)(W + o_W2);
    u16* whhf = (u16*)(W + o_whhf);
    u16* whhb = (u16*)(W + o_whhb);
    u16* a1wh = (u16*)(W + o_a1wh);
    u16* hb = (u16*)(W + o_hb);
    float* cenc = (float*)(W + o_cenc);
    u16* xcat = (u16*)(W + o_xcat);
    float* cdec = (float*)(W + o_cdec);
    float* pp = (float*)(W + o_pp);
    float* sc = (float*)(W + o_sc);
    unsigned* bar_enc = (unsigned*)(W + o_bar);          // uses +0/+64/+128/+192
    unsigned* bar_dec = (unsigned*)(W + o_bar + 256);    // uses +0/+64

    // zero recurrent state + barrier vars (ws is re-poisoned before every timed launch)
    hipMemsetAsync(hb, 0, (size_t)2 * 32 * 512 * 2, stream);      // parity-0 h, both dirs
    hipMemsetAsync(cenc, 0, (size_t)2 * 32 * 512 * 4, stream);
    hipMemsetAsync(W + o_bar, 0, 512, stream);

    // weight prep (fp32 -> bf16)
    convert_f2b<<<1024, 256, 0, stream>>>(eWhh_f, whhf, 2048 * 512);
    convert_f2b<<<1024, 256, 0, stream>>>(eWhh_b, whhb, 2048 * 512);
    build_w2<<<2048, 256, 0, stream>>>(dWih, dWhh, W2);
    build_a1wh<<<1536, 256, 0, stream>>>(a1W, a1wh);

    embed_src<<<800, 256, 0, stream>>>(src_tok, src_emb, xs);
    embed_tgt<<<800, 256, 0, stream>>>(tgt_tok, tgt_emb, clsin);

    // input projections
    gemm_bt<<<dim3(25, 16), 256, 0, stream>>>(xs, 512, eWih_f, 512, Pf, ebih_f, ebhh_f, 2048, 512, 0);
    gemm_bt<<<dim3(25, 16), 256, 0, stream>>>(xs, 512, eWih_b, 512, Pb, ebih_b, ebhh_b, 2048, 512, 0);
    gemm_bt<<<dim3(25, 16), 256, 0, stream>>>(clsin, 2048, dWih, 1536, Dpre, dbih, dbhh, 2048, 512, 0);

    // encoder recurrence: single persistent kernel (replaces 100 launches)
    enc_persist<<<128, 64, 0, stream>>>(whhf, whhb, Pf, Pb, hb, cenc, ef32, bar_enc);

    // attention enc-part: encpre = enc_out @ a1W[:, :1024]^T + a1b
    gemm_bt<<<dim3(25, 12), 256, 0, stream>>>(ef32, 1024, a1W, 1536, encpre, a1b, nullptr, 1536, 1024, 0);

    init_dec<<<64, 256, 0, stream>>>(hb, cenc, xcat, cdec);

    // decoder recurrence: single persistent kernel (replaces 400 launches)
    dec_persist<<<256, 256, 0, stream>>>(W2, a1wh, encpre, ef32, Dpre, a2W, a2b,
                                         pp, sc, xcat, cdec, clsin, bar_dec);

    // classifier
    gemm_bt<<<dim3(25, 8), 256, 0, stream>>>(clsin, 2048, c1W, 2048, h1, c1b, nullptr, 1024, 2048, 1);
    gemm_bt<<<dim3(25, 250), 256, 0, stream>>>(h1, 1024, c2W, 1024, out, c2b, nullptr, 32000, 1024, 0);
}

// Round 2
// 11170.313 us; speedup vs baseline: 2.2291x; 2.2291x over previous
//
#include <hip/hip_runtime.h>

typedef unsigned short u16;
typedef short bf16x8 __attribute__((ext_vector_type(8)));
typedef float f32x4 __attribute__((ext_vector_type(4)));

// B=32, S=T=100, E=512, H=512, VT=32000. fp32 in global; bf16 as MFMA operands.
// gate order (PyTorch): i,f,g,o rows of [4H, *] weights.

__device__ __forceinline__ u16 f2bf(float f) {
    unsigned u = __builtin_bit_cast(unsigned, f);
    return (u16)((u + 0x7FFFu + ((u >> 16) & 1u)) >> 16);
}
__device__ __forceinline__ float sigm(float x) { return 1.0f / (1.0f + __expf(-x)); }
__device__ __forceinline__ float tanh_(float x) { return 2.0f / (1.0f + __expf(-2.0f * x)) - 1.0f; }
__device__ __forceinline__ f32x4 mfma16(bf16x8 a, bf16x8 b, f32x4 c) {
    return __builtin_amdgcn_mfma_f32_16x16x32_bf16(a, b, c, 0, 0, 0);
}
__device__ __forceinline__ uint4 pack8(float4 a, float4 b) {
    union { u16 h[8]; uint4 v; } u;
    u.h[0] = f2bf(a.x); u.h[1] = f2bf(a.y); u.h[2] = f2bf(a.z); u.h[3] = f2bf(a.w);
    u.h[4] = f2bf(b.x); u.h[5] = f2bf(b.y); u.h[6] = f2bf(b.z); u.h[7] = f2bf(b.w);
    return u.v;
}

// ---- coherent (L1/L2-bypass) accessors: data lands at / comes from L3 (die-shared) ----
__device__ __forceinline__ void stg_sc_f32(float* p, float v) {
    asm volatile("global_store_dword %0, %1, off sc0 sc1" :: "v"(p), "v"(v));
}
__device__ __forceinline__ void stg_sc_u16(u16* p, unsigned v) {
    asm volatile("global_store_short %0, %1, off sc0 sc1" :: "v"(p), "v"(v));
}
__device__ __forceinline__ float ldg_sc_f32(const float* p) {   // NOT ready until VM_WAIT0
    float r;
    asm volatile("global_load_dword %0, %1, off sc0 sc1" : "=v"(r) : "v"(p));
    return r;
}
__device__ __forceinline__ bf16x8 ldg_sc_b128(const u16* p) {   // NOT ready until VM_WAIT0
    bf16x8 r;
    asm volatile("global_load_dwordx4 %0, %1, off sc0 sc1" : "=v"(r) : "v"(p));
    return r;
}
// after batched asm loads: wait + compile-time scheduling fence (rule #18)
#define VM_WAIT0 do { asm volatile("s_waitcnt vmcnt(0)" ::: "memory"); \
                      __builtin_amdgcn_sched_barrier(0); } while (0)

// ---- grid barrier: monotone counter, RELAXED atomics only, no cache maintenance ----
// All cross-block data moves via sc0/sc1 ops (already coherent at L3), so the barrier
// needs no fences. cnt is never reset (no reset/arrival race); cnt,flg in separate lines.
__device__ __forceinline__ void gbar(unsigned* cnt, unsigned* flg, unsigned gen, unsigned nb) {
    asm volatile("s_waitcnt vmcnt(0)" ::: "memory");   // each wave drains its sc-stores
    __syncthreads();
    if (threadIdx.x == 0) {
        unsigned a = __hip_atomic_fetch_add(cnt, 1u, __ATOMIC_RELAXED, __HIP_MEMORY_SCOPE_AGENT);
        if (a == gen * nb - 1u) {
            __hip_atomic_store(flg, gen, __ATOMIC_RELAXED, __HIP_MEMORY_SCOPE_AGENT);
        } else {
            long guard = 0;
            while (__hip_atomic_load(flg, __ATOMIC_RELAXED, __HIP_MEMORY_SCOPE_AGENT) < gen) {
                __builtin_amdgcn_s_sleep(1);
                if (++guard > (1L << 22)) break;   // fail loud, never hang
            }
        }
    }
    __syncthreads();
}

// ---------------- weight conversion ----------------
__global__ __launch_bounds__(256) void convert_f2b(const float* __restrict__ src,
                                                   u16* __restrict__ dst, int n) {
    int i = (blockIdx.x * 256 + threadIdx.x) * 4;
    if (i < n) {
        float4 v = *(const float4*)(src + i);
        dst[i] = f2bf(v.x); dst[i + 1] = f2bf(v.y);
        dst[i + 2] = f2bf(v.z); dst[i + 3] = f2bf(v.w);
    }
}
// W2[n][k] = k<1024 ? dec_Wih[n][512+k] : dec_Whh[n][k-1024]   (n in [0,2048))
__global__ __launch_bounds__(256) void build_w2(const float* __restrict__ Wih,
                                                const float* __restrict__ Whh,
                                                u16* __restrict__ W2) {
    int n = blockIdx.x;
    for (int i = 0; i < 6; i++) {
        int k = i * 256 + threadIdx.x;
        float v = (k < 1024) ? Wih[(size_t)n * 1536 + 512 + k]
                             : Whh[(size_t)n * 512 + (k - 1024)];
        W2[(size_t)n * 1536 + k] = f2bf(v);
    }
}
// a1Wh[n][k] = att1_W[n][1024+k], bf16, n<1536, k<512
__global__ __launch_bounds__(256) void build_a1wh(const float* __restrict__ a1W,
                                                  u16* __restrict__ dst) {
    int n = blockIdx.x;
    for (int i = 0; i < 2; i++) {
        int k = i * 256 + threadIdx.x;
        dst[(size_t)n * 512 + k] = f2bf(a1W[(size_t)n * 1536 + 1024 + k]);
    }
}

// ---------------- embedding gathers (fp32) ----------------
__global__ __launch_bounds__(256) void embed_src(const int* __restrict__ tok,
                                                 const float* __restrict__ emb,
                                                 float* __restrict__ xs) {
    int g = blockIdx.x * 256 + threadIdx.x;      // 3200*64
    int row = g >> 6, c = (g & 63) * 8;
    int s = row >> 5, b = row & 31;
    int id = tok[b * 100 + s];
    *(float4*)(xs + (size_t)row * 512 + c) = *(const float4*)(emb + (size_t)id * 512 + c);
    *(float4*)(xs + (size_t)row * 512 + c + 4) = *(const float4*)(emb + (size_t)id * 512 + c + 4);
}
__global__ __launch_bounds__(256) void embed_tgt(const int* __restrict__ tok,
                                                 const float* __restrict__ emb,
                                                 float* __restrict__ cls_in) {
    int g = blockIdx.x * 256 + threadIdx.x;
    int row = g >> 6, c = (g & 63) * 8;
    int t = row >> 5, b = row & 31;
    int id = tok[b * 100 + t];
    size_t dst = ((size_t)b * 100 + t) * 2048 + c;
    *(float4*)(cls_in + dst) = *(const float4*)(emb + (size_t)id * 512 + c);
    *(float4*)(cls_in + dst + 4) = *(const float4*)(emb + (size_t)id * 512 + c + 4);
}

// ---------------- MFMA GEMM: C[M,N] = A[M,K]@W[N,K]^T (+bias)(+relu) ----------------
__global__ __launch_bounds__(256) void gemm_bt(const float* __restrict__ A, int lda,
                                               const float* __restrict__ W, int ldw,
                                               float* __restrict__ C,
                                               const float* __restrict__ bias0,
                                               const float* __restrict__ bias1,
                                               int N, int K, int relu) {
    __shared__ __align__(16) u16 As[128][40];
    __shared__ __align__(16) u16 Bs[128][40];
    int tid = threadIdx.x;
    int lane = tid & 63, w = tid >> 6;
    int wm = w & 1, wn = w >> 1;
    int l15 = lane & 15, q = lane >> 4;
    f32x4 acc[4][4] = {};
    int sr = tid >> 2, sc = (tid & 3) * 8;
    const float* Ar0 = A + (size_t)(blockIdx.x * 128 + sr) * lda;
    const float* Ar1 = Ar0 + (size_t)64 * lda;
    const float* Wr0 = W + (size_t)(blockIdx.y * 128 + sr) * ldw;
    const float* Wr1 = Wr0 + (size_t)64 * ldw;
    for (int kb = 0; kb < K; kb += 32) {
        *(uint4*)&As[sr][sc] = pack8(*(const float4*)(Ar0 + kb + sc), *(const float4*)(Ar0 + kb + sc + 4));
        *(uint4*)&As[sr + 64][sc] = pack8(*(const float4*)(Ar1 + kb + sc), *(const float4*)(Ar1 + kb + sc + 4));
        *(uint4*)&Bs[sr][sc] = pack8(*(const float4*)(Wr0 + kb + sc), *(const float4*)(Wr0 + kb + sc + 4));
        *(uint4*)&Bs[sr + 64][sc] = pack8(*(const float4*)(Wr1 + kb + sc), *(const float4*)(Wr1 + kb + sc + 4));
        __syncthreads();
        bf16x8 af[4], bfr[4];
        for (int i = 0; i < 4; i++) af[i] = *(const bf16x8*)&As[wm * 64 + i * 16 + l15][q * 8];
        for (int j = 0; j < 4; j++) bfr[j] = *(const bf16x8*)&Bs[wn * 64 + j * 16 + l15][q * 8];
        for (int i = 0; i < 4; i++)
            for (int j = 0; j < 4; j++) acc[i][j] = mfma16(af[i], bfr[j], acc[i][j]);
        __syncthreads();
    }
    for (int j = 0; j < 4; j++) {
        int n = blockIdx.y * 128 + wn * 64 + j * 16 + l15;
        float bv = 0.f;
        if (bias0) bv += bias0[n];
        if (bias1) bv += bias1[n];
        for (int i = 0; i < 4; i++) {
            int mb = blockIdx.x * 128 + wm * 64 + i * 16 + q * 4;
            for (int r = 0; r < 4; r++) {
                float v = acc[i][j][r] + bv;
                if (relu) v = v > 0.f ? v : 0.f;
                C[(size_t)(mb + r) * N + n] = v;
            }
        }
    }
}

// ---------------- persistent encoder: all 100 steps, Whh pinned in LDS ----------------
// grid = 128 blocks x 64 thr. block = (dir, mt, jt). per-dir grid barrier.
// cross-block traffic (h ping-pong) via sc0/sc1; Pf/Pb plain (stay warm in L2).
__global__ __launch_bounds__(64) void enc_persist(const u16* __restrict__ whhf,
                                                  const u16* __restrict__ whhb,
                                                  const float* __restrict__ Pf,
                                                  const float* __restrict__ Pb,
                                                  u16* __restrict__ hb,       // [parity][dir][32][512] bf16
                                                  float* __restrict__ cenc,   // [dir][32][512] fp32
                                                  float* __restrict__ ef32,   // [b][s][1024] fp32
                                                  unsigned* __restrict__ bar) {
    __shared__ __align__(16) u16 ws[64 * 512];   // 64KB
    int blk = blockIdx.x;
    int dir = blk >> 6, mt = (blk >> 5) & 1, jt = blk & 31;
    int lane = threadIdx.x, l15 = lane & 15, q = lane >> 4;
    const u16* whh = dir ? whhb : whhf;
    const float* P = dir ? Pb : Pf;
    unsigned* cnt = bar + dir * 32;      // 128B apart per dir
    unsigned* flg = cnt + 16;
    {
        int R = lane, g = R >> 4, r15 = R & 15;
        const u16* src = whh + (size_t)(g * 512 + jt * 16 + r15) * 512;
        int swz = (R & 7) * 8;
        for (int c = 0; c < 64; c++)
            *(uint4*)&ws[R * 512 + ((c * 8) ^ swz)] = *(const uint4*)(src + c * 8);
    }
    __syncthreads();
    int swzr = (l15 & 7) * 8;
    unsigned gen = 0;
    for (int t = 0; t < 100; t++) {
        const u16* hin = hb + ((t & 1) ? 2 * 32 * 512 : 0) + dir * 32 * 512;
        u16* hout = hb + ((t & 1) ? 0 : 2 * 32 * 512);
        int s = dir ? (99 - t) : t;
        const u16* arow = hin + (mt * 16 + l15) * 512 + q * 8;
        bf16x8 afr[16];
#pragma unroll
        for (int kk = 0; kk < 16; kk++) afr[kk] = ldg_sc_b128(arow + kk * 32);
        VM_WAIT0;
        f32x4 acc[4] = {};
#pragma unroll
        for (int kk = 0; kk < 16; kk++) {
            int kb = kk * 32;
#pragma unroll
            for (int g = 0; g < 4; g++) {
                bf16x8 b = *(const bf16x8*)&ws[(g * 16 + l15) * 512 + ((kb + q * 8) ^ swzr)];
                acc[g] = mfma16(afr[kk], b, acc[g]);
            }
        }
        int j = jt * 16 + l15;
        for (int r = 0; r < 4; r++) {
            int b_ = mt * 16 + q * 4 + r;
            const float* Pr = P + ((size_t)s * 32 + b_) * 2048;
            float gi = acc[0][r] + Pr[j];
            float gf = acc[1][r] + Pr[512 + j];
            float gg = acc[2][r] + Pr[1024 + j];
            float go = acc[3][r] + Pr[1536 + j];
            float* cp = cenc + (dir * 32 + b_) * 512 + j;      // block-private
            float cn = sigm(gf) * (*cp) + sigm(gi) * tanh_(gg);
            float hn = sigm(go) * tanh_(cn);
            *cp = cn;
            stg_sc_u16(&hout[(dir * 32 + b_) * 512 + j], f2bf(hn));
            ef32[((size_t)b_ * 100 + s) * 1024 + dir * 512 + j] = hn;   // read post-kernel
        }
        if (t < 99) { gen++; gbar(cnt, flg, gen, 64); }
    }
}

// decoder init: h/c from final forward-direction encoder state
__global__ __launch_bounds__(256) void init_dec(const u16* __restrict__ h_enc,
                                                const float* __restrict__ c_enc,
                                                u16* __restrict__ xcat0,
                                                float* __restrict__ c_dec) {
    int idx = blockIdx.x * 256 + threadIdx.x;    // 16384 = 32*512
    int b = idx >> 9, j = idx & 511;
    xcat0[b * 1536 + 1024 + j] = h_enc[b * 512 + j];
    c_dec[idx] = c_enc[idx];
}

// ---------------- persistent decoder: all 100 steps, W2 + a1Wh pinned in LDS ----------
// grid = 128 blocks x 256 thr.
// phase A (blocks<96, waves 0-1): pp = h @ a1Wh^T        -> bar
// phase B (all): block owns 25 rows of one batch; pp[b] staged in LDS -> bar
// phase C (all): softmax + ctx (b=B0>>2, 256-col chunk)  -> bar
// phase D (all, waves 0-1): gates MFMA + LSTM update     -> bar
// cross-block buffers (pp, sc, xcat) via sc0/sc1; encpre/ef32/Dpre plain (L2-warm).
__global__ __launch_bounds__(256) void dec_persist(const u16* __restrict__ W2g,
                                                   const u16* __restrict__ a1whg,
                                                   const float* __restrict__ encpre,
                                                   const float* __restrict__ ef32,
                                                   const float* __restrict__ Dpre,
                                                   const float* __restrict__ a2W,
                                                   const float* __restrict__ a2b,
                                                   float* __restrict__ pp,
                                                   float* __restrict__ sc,
                                                   u16* __restrict__ xcat,
                                                   float* __restrict__ cdec,
                                                   float* __restrict__ clsin,
                                                   unsigned* __restrict__ bar) {
    __shared__ __align__(16) u16 w2s[16 * 1536];   // 48KB
    __shared__ __align__(16) u16 a1s[16 * 512];    // 16KB
    __shared__ float a2s[1536];
    __shared__ float pps[1536];
    __shared__ float gbuf[32 * 16];
    __shared__ float sm[100];
    __shared__ float rmax_s, rsum_s;
    int B0 = blockIdx.x, tid = threadIdx.x;
    int w = tid >> 6, lane = tid & 63, l15 = lane & 15, q = lane >> 4;
    unsigned* cnt = bar;
    unsigned* flg = bar + 16;
    int swzr = (l15 & 7) * 8;

    for (int k = tid; k < 1536; k += 256) a2s[k] = a2W[k];
    float a2bv = a2b[0];
    {   // W2 slice (row n <-> global row (n>>2)*512 + B0*4 + (n&3))
        int j0 = B0 * 4;
        for (int r = 0; r < 16; r++) {
            if (tid < 192) {
                int grow = (r >> 2) * 512 + j0 + (r & 3);
                *(uint4*)&w2s[r * 1536 + ((tid * 8) ^ ((r & 7) * 8))] =
                    *(const uint4*)(W2g + (size_t)grow * 1536 + tid * 8);
            }
        }
    }
    if (B0 < 96) {       // a1Wh slice rows n0..n0+15
        int n0 = B0 * 16;
        for (int r = 0; r < 16; r++) {
            if (tid < 64) {
                *(uint4*)&a1s[r * 512 + ((tid * 8) ^ ((r & 7) * 8))] =
                    *(const uint4*)(a1whg + (size_t)(n0 + r) * 512 + tid * 8);
            }
        }
    }
    __syncthreads();

    unsigned gen = 0;
    for (int t = 0; t < 100; t++) {
        u16* xin = xcat + (size_t)(t & 1) * 32 * 1536;
        u16* xnext = xcat + (size_t)((t + 1) & 1) * 32 * 1536;

        // ---- phase A: pp[32][1536] = h @ a1Wh^T (same accumulation order as before)
        if (B0 < 96 && w < 2) {
            int m = w;
            const u16* arow = xin + (m * 16 + l15) * 1536 + 1024 + q * 8;
            bf16x8 afr[16];
#pragma unroll
            for (int kk = 0; kk < 16; kk++) afr[kk] = ldg_sc_b128(arow + kk * 32);
            VM_WAIT0;
            f32x4 acc = {};
#pragma unroll
            for (int kk = 0; kk < 16; kk++) {
                bf16x8 b = *(const bf16x8*)&a1s[l15 * 512 + ((kk * 32 + q * 8) ^ swzr)];
                acc = mfma16(afr[kk], b, acc);
            }
            int n = B0 * 16 + l15;
            for (int r = 0; r < 4; r++) stg_sc_f32(&pp[(m * 16 + q * 4 + r) * 1536 + n], acc[r]);
        }
        gen++; gbar(cnt, flg, gen, 128);

        // ---- phase B: scores. block owns rows [B0*25, B0*25+25), all in batch B0>>2.
        {
            int bb = B0 >> 2;
            float ppv[6];
#pragma unroll
            for (int i2 = 0; i2 < 6; i2++) ppv[i2] = ldg_sc_f32(&pp[bb * 1536 + i2 * 256 + tid]);
            VM_WAIT0;
#pragma unroll
            for (int i2 = 0; i2 < 6; i2++) pps[i2 * 256 + tid] = ppv[i2];
            __syncthreads();
            for (int i2 = 0; i2 < 7; i2++) {
                int rl = w + 4 * i2;
                if (rl < 25) {
                    int row = B0 * 25 + rl;
                    const float* ep = encpre + (size_t)row * 1536;
                    float acc = 0.f;
                    for (int ii = 0; ii < 24; ii++) {
                        int k = ii * 64 + lane;
                        float v = ep[k] + pps[k];
                        v = fmaxf(v, 0.f);
                        acc += v * a2s[k];
                    }
                    for (int off = 32; off; off >>= 1) acc += __shfl_xor(acc, off);
                    if (lane == 0) stg_sc_f32(&sc[row], acc + a2bv);
                }
            }
        }
        gen++; gbar(cnt, flg, gen, 128);

        // ---- phase C: softmax over s + ctx; b = B0>>2, 256-col chunk
        {
            int b = B0 >> 2, kc = (B0 & 3) * 256;
            float sv = 0.f;
            if (tid < 100) sv = ldg_sc_f32(&sc[b * 100 + tid]);
            VM_WAIT0;
            if (tid < 100) sm[tid] = sv;
            __syncthreads();
            if (tid < 64) {
                float mx = -1e30f;
                for (int s2 = tid; s2 < 100; s2 += 64) mx = fmaxf(mx, sm[s2]);
                for (int o = 32; o; o >>= 1) mx = fmaxf(mx, __shfl_xor(mx, o));
                if (tid == 0) rmax_s = mx;
            }
            __syncthreads();
            if (tid < 100) sm[tid] = __expf(sm[tid] - rmax_s);
            __syncthreads();
            if (tid < 64) {
                float s3 = 0.f;
                for (int s2 = tid; s2 < 100; s2 += 64) s3 += sm[s2];
                for (int o = 32; o; o >>= 1) s3 += __shfl_xor(s3, o);
                if (tid == 0) rsum_s = s3;
            }
            __syncthreads();
            float inv = 1.0f / rsum_s;
            int k = kc + tid;
            const float* eb = ef32 + (size_t)b * 100 * 1024 + k;
            float acc = 0.f;
            for (int s2 = 0; s2 < 100; s2++) acc += sm[s2] * eb[s2 * 1024];
            acc *= inv;
            stg_sc_u16(&xin[b * 1536 + k], f2bf(acc));
            clsin[((size_t)b * 100 + t) * 2048 + 512 + k] = acc;   // read post-kernel
        }
        gen++; gbar(cnt, flg, gen, 128);

        // ---- phase D: gates = xcat @ W2^T + Dpre, LSTM update (order unchanged)
        {
            int j0 = B0 * 4;
            if (w < 2) {
                int m = w;
                const u16* arow = xin + (m * 16 + l15) * 1536 + q * 8;
                f32x4 acc = {};
                for (int g3 = 0; g3 < 3; g3++) {
                    bf16x8 afr[16];
#pragma unroll
                    for (int kk = 0; kk < 16; kk++)
                        afr[kk] = ldg_sc_b128(arow + (g3 * 16 + kk) * 32);
                    VM_WAIT0;
#pragma unroll
                    for (int kk = 0; kk < 16; kk++) {
                        int kb = (g3 * 16 + kk) * 32;
                        bf16x8 b = *(const bf16x8*)&w2s[l15 * 1536 + ((kb + q * 8) ^ swzr)];
                        acc = mfma16(afr[kk], b, acc);
                    }
                }
                for (int r = 0; r < 4; r++) gbuf[(m * 16 + q * 4 + r) * 16 + l15] = acc[r];
            }
            __syncthreads();
            if (tid < 128) {
                int b = tid >> 2, jo = tid & 3, j = j0 + jo;
                const float* Pr = Dpre + ((size_t)b * 100 + t) * 2048;
                float gi = gbuf[b * 16 + jo] + Pr[j];
                float gf = gbuf[b * 16 + 4 + jo] + Pr[512 + j];
                float gg = gbuf[b * 16 + 8 + jo] + Pr[1024 + j];
                float go = gbuf[b * 16 + 12 + jo] + Pr[1536 + j];
                float cv = cdec[b * 512 + j];                 // block-private across steps
                float cn = sigm(gf) * cv + sigm(gi) * tanh_(gg);
                float hn = sigm(go) * tanh_(cn);
                cdec[b * 512 + j] = cn;
                stg_sc_u16(&xnext[b * 1536 + 1024 + j], f2bf(hn));
                clsin[((size_t)b * 100 + t) * 2048 + 1536 + j] = hn;   // read post-kernel
            }
        }
        if (t < 99) { gen++; gbar(cnt, flg, gen, 128); }
    }
}

extern "C" void kernel_launch(void* const* d_in, const int* in_sizes, int n_in,
                              void* d_out, int out_size, void* d_ws, size_t ws_size,
                              hipStream_t stream) {
    const int* src_tok = (const int*)d_in[0];
    const int* tgt_tok = (const int*)d_in[1];
    const float* src_emb = (const float*)d_in[2];
    const float* tgt_emb = (const float*)d_in[3];
    const float* eWih_f = (const float*)d_in[4];
    const float* eWhh_f = (const float*)d_in[5];
    const float* ebih_f = (const float*)d_in[6];
    const float* ebhh_f = (const float*)d_in[7];
    const float* eWih_b = (const float*)d_in[8];
    const float* eWhh_b = (const float*)d_in[9];
    const float* ebih_b = (const float*)d_in[10];
    const float* ebhh_b = (const float*)d_in[11];
    const float* dWih = (const float*)d_in[12];
    const float* dWhh = (const float*)d_in[13];
    const float* dbih = (const float*)d_in[14];
    const float* dbhh = (const float*)d_in[15];
    const float* a1W = (const float*)d_in[16];
    const float* a1b = (const float*)d_in[17];
    const float* a2W = (const float*)d_in[18];
    const float* a2b = (const float*)d_in[19];
    const float* c1W = (const float*)d_in[20];
    const float* c1b = (const float*)d_in[21];
    const float* c2W = (const float*)d_in[22];
    const float* c2b = (const float*)d_in[23];
    float* out = (float*)d_out;

    char* W = (char*)d_ws;
    size_t off = 0;
    auto alloc = [&](size_t bytes) { size_t o = off; off = (off + bytes + 255) & ~(size_t)255; return o; };
    size_t o_xs     = alloc((size_t)3200 * 512 * 4);
    size_t o_Pf     = alloc((size_t)3200 * 2048 * 4);
    size_t o_Pb     = alloc((size_t)3200 * 2048 * 4);
    size_t o_Dpre   = alloc((size_t)3200 * 2048 * 4);
    size_t o_ef32   = alloc((size_t)3200 * 1024 * 4);
    size_t o_encpre = alloc((size_t)3200 * 1536 * 4);
    size_t o_clsin  = alloc((size_t)3200 * 2048 * 4);
    size_t o_h1     = alloc((size_t)3200 * 1024 * 4);
    size_t o_W2     = alloc((size_t)2048 * 1536 * 2);
    size_t o_whhf   = alloc((size_t)2048 * 512 * 2);
    size_t o_whhb   = alloc((size_t)2048 * 512 * 2);
    size_t o_a1wh   = alloc((size_t)1536 * 512 * 2);
    size_t o_hb     = alloc((size_t)2 * 2 * 32 * 512 * 2);   // [parity][dir][b][k] bf16
    size_t o_cenc   = alloc((size_t)2 * 32 * 512 * 4);
    size_t o_xcat   = alloc((size_t)2 * 32 * 1536 * 2);      // [parity][b][ctx(1024)|h(512)] bf16
    size_t o_cdec   = alloc((size_t)32 * 512 * 4);
    size_t o_pp     = alloc((size_t)32 * 1536 * 4);
    size_t o_sc     = alloc((size_t)3200 * 4);
    size_t o_bar    = alloc(512);                            // grid-barrier counters/flags

    float* xs = (float*)(W + o_xs);
    float* Pf = (float*)(W + o_Pf);
    float* Pb = (float*)(W + o_Pb);
    float* Dpre = (float*)(W + o_Dpre);
    float* ef32 = (float*)(W + o_ef32);
    float* encpre = (float*)(W + o_encpre);
    float* clsin = (float*)(W + o_clsin);
    float* h1 = (float*)(W + o_h1);
    u16* W2 = (u16*)(W + o_W2);
    u16* whhf = (u16*)(W + o_whhf);
    u16* whhb = (u16*)(W + o_whhb);
    u16* a1wh = (u16*)(W + o_a1wh);
    u16* hb = (u16*)(W + o_hb);
    float* cenc = (float*)(W + o_cenc);
    u16* xcat = (u16*)(W + o_xcat);
    float* cdec = (float*)(W + o_cdec);
    float* pp = (float*)(W + o_pp);
    float* sc = (float*)(W + o_sc);
    unsigned* bar_enc = (unsigned*)(W + o_bar);          // dir0 at +0/+64, dir1 at +128/+192
    unsigned* bar_dec = (unsigned*)(W + o_bar + 256);    // +0/+64

    // zero recurrent state + barrier vars (ws is re-poisoned before every timed launch)
    hipMemsetAsync(hb, 0, (size_t)2 * 32 * 512 * 2, stream);      // parity-0 h, both dirs
    hipMemsetAsync(cenc, 0, (size_t)2 * 32 * 512 * 4, stream);
    hipMemsetAsync(W + o_bar, 0, 512, stream);

    // weight prep (fp32 -> bf16)
    convert_f2b<<<1024, 256, 0, stream>>>(eWhh_f, whhf, 2048 * 512);
    convert_f2b<<<1024, 256, 0, stream>>>(eWhh_b, whhb, 2048 * 512);
    build_w2<<<2048, 256, 0, stream>>>(dWih, dWhh, W2);
    build_a1wh<<<1536, 256, 0, stream>>>(a1W, a1wh);

    embed_src<<<800, 256, 0, stream>>>(src_tok, src_emb, xs);
    embed_tgt<<<800, 256, 0, stream>>>(tgt_tok, tgt_emb, clsin);

    // input projections
    gemm_bt<<<dim3(25, 16), 256, 0, stream>>>(xs, 512, eWih_f, 512, Pf, ebih_f, ebhh_f, 2048, 512, 0);
    gemm_bt<<<dim3(25, 16), 256, 0, stream>>>(xs, 512, eWih_b, 512, Pb, ebih_b, ebhh_b, 2048, 512, 0);
    gemm_bt<<<dim3(25, 16), 256, 0, stream>>>(clsin, 2048, dWih, 1536, Dpre, dbih, dbhh, 2048, 512, 0);

    // encoder recurrence: single persistent kernel
    enc_persist<<<128, 64, 0, stream>>>(whhf, whhb, Pf, Pb, hb, cenc, ef32, bar_enc);

    // attention enc-part: encpre = enc_out @ a1W[:, :1024]^T + a1b
    gemm_bt<<<dim3(25, 12), 256, 0, stream>>>(ef32, 1024, a1W, 1536, encpre, a1b, nullptr, 1536, 1024, 0);

    init_dec<<<64, 256, 0, stream>>>(hb, cenc, xcat, cdec);

    // decoder recurrence: single persistent kernel
    dec_persist<<<128, 256, 0, stream>>>(W2, a1wh, encpre, ef32, Dpre, a2W, a2b,
                                         pp, sc, xcat, cdec, clsin, bar_dec);

    // classifier
    gemm_bt<<<dim3(25, 8), 256, 0, stream>>>(clsin, 2048, c1W, 2048, h1, c1b, nullptr, 1024, 2048, 1);
    gemm_bt<<<dim3(25, 250), 256, 0, stream>>>(h1, 1024, c2W, 1024, out, c2b, nullptr, 32000, 1024, 0);
}